// Round 1
// baseline (1098.013 us; speedup 1.0000x reference)
//
#include <hip/hip_runtime.h>
#include <math.h>

#define T_DIM 4096
#define B_DIM 8
#define C_DIM 1024
#define H_DIM 16
#define K_DIM 31
#define PAD_L 30
#define TILE_T 32
#define WIN (TILE_T + K_DIM - 1)   // 62
#define BLOCK 256
#define DPTH 8                     // prefetch ring depth (power of 2)

// One thread per (b,c) column, TILE_T consecutive t per thread.
// Lanes -> consecutive c -> fully coalesced 256B/wave accesses.
// A wave spans exactly one head (R = C/H = 64): taps are wave-uniform SGPRs.
//
// R4 restructure: the R3 "batch 62 loads + sched_barrier" plan was defeated by
// the compiler (VGPR=40 => window was NOT held in arch VGPRs; either AGPR
// round-trips or JIT load sinking => latency-bound at 81us, VALUBusy 44%).
// New shape = explicit accumulator streaming: 32 persistent accumulators,
// one x value consumed per step, prefetch ring of depth 8 issued D steps
// ahead in program order. ~48 VGPR -> 8 waves/SIMD, ~8 loads in flight/wave.
// Loads use uniform-base + 32-bit lane offset (saddr form): 0 VALU addr math.
__global__ __launch_bounds__(BLOCK, 6) void lightconv_kernel(
    const float* __restrict__ x,
    const float* __restrict__ w,
    float* __restrict__ out)
{
    __shared__ float s_taps[4][K_DIM];   // 4 heads per 256-thread block

    const int tid    = threadIdx.x;
    const int colBlk = blockIdx.x;       // 0..31  (B*C / BLOCK)
    const int tBlk   = blockIdx.y;       // 0..127 (T / TILE_T)
    const unsigned cc = colBlk * BLOCK + tid;   // flat b*C + c
    const int t0     = tBlk * TILE_T;

    // ---- per-block softmax of the block's 4 heads (threads 0..3) ----
    if (tid < 4) {
        const int c0 = (colBlk * BLOCK) % C_DIM;   // multiple of 256
        const int h  = (c0 >> 6) + tid;            // head index
        const float* wr = w + h * K_DIM;
        float m = -1e30f;
        #pragma unroll
        for (int k = 0; k < K_DIM; ++k) m = fmaxf(m, wr[k]);
        float s = 0.0f;
        #pragma unroll
        for (int k = 0; k < K_DIM; ++k) {
            float e = __expf(wr[k] - m);
            s_taps[tid][k] = e;
            s += e;
        }
        const float inv = 1.0f / s;
        #pragma unroll
        for (int k = 0; k < K_DIM; ++k) s_taps[tid][k] *= inv;
    }
    __syncthreads();

    // ---- taps -> SGPRs (wave-uniform: one head per wave) ----
    const int hl = tid >> 6;
    float taps[K_DIM];
    #pragma unroll
    for (int k = 0; k < K_DIM; ++k) {
        taps[k] = __int_as_float(
            __builtin_amdgcn_readfirstlane(__float_as_int(s_taps[hl][k])));
    }

    const long stride = (long)B_DIM * C_DIM;   // 8192 elems between t's

    // Uniform (SGPR) bases + per-lane 32-bit offset cc -> saddr addressing.
    const float* pb = x   + (long)(t0 - PAD_L) * stride;
    float*       po = out + (long)t0 * stride;

    float acc[TILE_T];
    #pragma unroll
    for (int i = 0; i < TILE_T; ++i) acc[i] = 0.0f;

    float ring[DPTH];

    if (t0 >= PAD_L) {                         // wave-uniform: all tBlk >= 1
        #pragma unroll
        for (int j = 0; j < DPTH; ++j)
            ring[j] = pb[(long)j * stride + cc];
        #pragma unroll
        for (int j = 0; j < WIN; ++j) {
            const float xj = ring[j & (DPTH - 1)];
            if (j + DPTH < WIN)                // compile-time after unroll
                ring[j & (DPTH - 1)] = pb[(long)(j + DPTH) * stride + cc];
            #pragma unroll
            for (int i = 0; i < TILE_T; ++i) {
                const int k = j - i;           // folds to consts after unroll
                if (k >= 0 && k < K_DIM)
                    acc[i] = fmaf(taps[k], xj, acc[i]);
            }
        }
    } else {                                   // only tBlk == 0 pays the guard
        #pragma unroll
        for (int j = 0; j < DPTH; ++j)
            ring[j] = (j < PAD_L) ? 0.0f : pb[(long)j * stride + cc];
        #pragma unroll
        for (int j = 0; j < WIN; ++j) {
            const float xj = ring[j & (DPTH - 1)];
            if (j + DPTH < WIN)
                ring[j & (DPTH - 1)] = ((j + DPTH) < PAD_L)
                    ? 0.0f : pb[(long)(j + DPTH) * stride + cc];
            #pragma unroll
            for (int i = 0; i < TILE_T; ++i) {
                const int k = j - i;
                if (k >= 0 && k < K_DIM)
                    acc[i] = fmaf(taps[k], xj, acc[i]);
            }
        }
    }

    // nontemporal: out is never re-read; don't let it evict x from L3
    #pragma unroll
    for (int i = 0; i < TILE_T; ++i)
        __builtin_nontemporal_store(acc[i], po + (long)i * stride + cc);
}

extern "C" void kernel_launch(void* const* d_in, const int* in_sizes, int n_in,
                              void* d_out, int out_size, void* d_ws, size_t ws_size,
                              hipStream_t stream) {
    const float* x = (const float*)d_in[0];    // [T, B, C] fp32
    const float* w = (const float*)d_in[1];    // [H, K]    fp32
    float* out = (float*)d_out;                // [T, B, C] fp32

    dim3 grid((B_DIM * C_DIM) / BLOCK, T_DIM / TILE_T);  // (32, 128)
    lightconv_kernel<<<grid, BLOCK, 0, stream>>>(x, w, out);
}

// Round 2
// 230.988 us; speedup vs baseline: 4.7535x; 4.7535x over previous
//
#include <hip/hip_runtime.h>
#include <math.h>

#define T_DIM 4096
#define B_DIM 8
#define C_DIM 1024
#define H_DIM 16
#define K_DIM 31
#define PAD_L 30
#define TILE_T 32
#define WIN (TILE_T + K_DIM - 1)   // 62
#define BLOCK 256

typedef __attribute__((ext_vector_type(4))) float f32x4;

// Async global->LDS DMA, 16 B per lane (one instr stages a full 1 KB row:
// 64 lanes x 16 B). LDS dest is wave-uniform base + lane*16 (linear layout).
__device__ __forceinline__ void stage16(const float* g, float* l) {
    __builtin_amdgcn_global_load_lds(
        (const __attribute__((address_space(1))) void*)g,
        (__attribute__((address_space(3))) void*)l,
        16, 0, 0);
}

// One window row J: 1 ds_read_b32 (immediate offset J*1024) feeding up to 31
// accumulators. J is a template parameter => taps[J-i] and acc[i] are indexed
// by compile-time constants ONLY (R4 lesson: runtime-indexed private arrays
// went to scratch -> 953us. Template recursion makes unroll structural.)
template <int J>
__device__ __forceinline__ void conv_step(const float* col,
                                          const float (&taps)[K_DIM],
                                          float (&acc)[TILE_T]) {
    const float xj = col[J * BLOCK];
    #pragma unroll
    for (int i = 0; i < TILE_T; ++i) {
        if (J - i >= 0 && J - i < K_DIM)
            acc[i] = fmaf(taps[J - i], xj, acc[i]);
    }
}

template <int J>
__device__ __forceinline__ void conv_all(const float* col,
                                         const float (&taps)[K_DIM],
                                         float (&acc)[TILE_T]) {
    if constexpr (J < WIN) {
        conv_step<J>(col, taps, acc);
        conv_all<J + 1>(col, taps, acc);
    }
}

// One thread per (b,c) column, TILE_T consecutive t per thread.
// x tile [WIN][256] staged into LDS via global_load_lds (async, no VGPR
// round-trip, can't be defeated by regalloc). ds_read_b32 column reads are
// conflict-free (bank = lane%32, 2-way aliasing = free).
__global__ __launch_bounds__(BLOCK, 2) void lightconv_kernel(
    const float* __restrict__ x,
    const float* __restrict__ w,
    float* __restrict__ out)
{
    __shared__ float tile[WIN][BLOCK];   // 63488 B
    __shared__ float s_taps[4][K_DIM];

    const int tid    = threadIdx.x;
    const int lane   = tid & 63;
    const int wv     = tid >> 6;
    const int colBlk = blockIdx.x;       // 0..31  (B*C / BLOCK)
    const int tBlk   = blockIdx.y;       // 0..127 (T / TILE_T)
    const int t0     = tBlk * TILE_T;
    const long stride = (long)B_DIM * C_DIM;   // 8192 elems between t's

    // ---- issue async staging FIRST: latency hides under the softmax ----
    // wave wv stages rows wv*16 .. wv*16+15 (wave 3: 14 rows).
    {
        const float* gbase = x + (long)(t0 - PAD_L) * stride
                               + colBlk * BLOCK + lane * 4;
        #pragma unroll
        for (int i = 0; i < 16; ++i) {
            const int r = wv * 16 + i;                 // wave-uniform
            if (r < WIN) {
                if (t0 - PAD_L + r >= 0) {             // uniform: only tBlk==0 pads
                    stage16(gbase + (long)r * stride, &tile[r][0]);
                } else {
                    const f32x4 z = {0.0f, 0.0f, 0.0f, 0.0f};
                    *(f32x4*)&tile[r][lane * 4] = z;
                }
            }
        }
    }

    // ---- per-block softmax of the block's 4 heads (threads 0..3) ----
    if (tid < 4) {
        const int c0 = (colBlk * BLOCK) % C_DIM;   // multiple of 256
        const int h  = (c0 >> 6) + tid;            // head index
        const float* wr = w + h * K_DIM;
        float m = -1e30f;
        #pragma unroll
        for (int k = 0; k < K_DIM; ++k) m = fmaxf(m, wr[k]);
        float s = 0.0f;
        #pragma unroll
        for (int k = 0; k < K_DIM; ++k) {
            float e = __expf(wr[k] - m);
            s_taps[tid][k] = e;
            s += e;
        }
        const float inv = 1.0f / s;
        #pragma unroll
        for (int k = 0; k < K_DIM; ++k) s_taps[tid][k] *= inv;
    }

    // drains vmcnt (staging DMA) + lgkmcnt, then barrier
    __syncthreads();

    // ---- taps -> SGPRs (wave-uniform: one head per wave) ----
    float taps[K_DIM];
    #pragma unroll
    for (int k = 0; k < K_DIM; ++k) {
        taps[k] = __int_as_float(
            __builtin_amdgcn_readfirstlane(__float_as_int(s_taps[wv][k])));
    }

    // ---- stream 62 LDS rows through 32 accumulators ----
    float acc[TILE_T];
    #pragma unroll
    for (int i = 0; i < TILE_T; ++i) acc[i] = 0.0f;

    conv_all<0>(&tile[0][0] + tid, taps, acc);

    // ---- store: nontemporal (out never re-read; don't evict x from L3) ----
    float* po = out + (long)t0 * stride + (colBlk * BLOCK + tid);
    #pragma unroll
    for (int i = 0; i < TILE_T; ++i)
        __builtin_nontemporal_store(acc[i], po + (long)i * stride);
}

extern "C" void kernel_launch(void* const* d_in, const int* in_sizes, int n_in,
                              void* d_out, int out_size, void* d_ws, size_t ws_size,
                              hipStream_t stream) {
    const float* x = (const float*)d_in[0];    // [T, B, C] fp32
    const float* w = (const float*)d_in[1];    // [H, K]    fp32
    float* out = (float*)d_out;                // [T, B, C] fp32

    dim3 grid((B_DIM * C_DIM) / BLOCK, T_DIM / TILE_T);  // (32, 128)
    lightconv_kernel<<<grid, BLOCK, 0, stream>>>(x, w, out);
}